// Round 7
// baseline (403.160 us; speedup 1.0000x reference)
//
#include <hip/hip_runtime.h>
#include <hip/hip_bf16.h>
#include <stdint.h>

#define B_SZ 8192
#define D_SZ 1024
#define H_SZ 1024
#define O_SZ 512
#define E_SZ 8

typedef float f32x4 __attribute__((ext_vector_type(4)));
typedef __bf16 bf16x8 __attribute__((ext_vector_type(8)));

typedef __attribute__((address_space(1))) uint32_t gu32;
typedef __attribute__((address_space(3))) uint32_t lu32;

__device__ __forceinline__ unsigned short f2bf(float f) {
    union { __hip_bfloat16 h; unsigned short u; } c;
    c.h = __float2bfloat16(f);
    return c.u;
}
__device__ __forceinline__ float bf2f(unsigned short u) {
    union { float f; uint32_t u; } c;
    c.u = ((uint32_t)u) << 16;
    return c.f;
}

// ------- fused: convert x row to bf16 AND 20 gate logits + 3 softmaxes -------
// 4 waves/block, one x-row per wave. Lane l handles d = l, l+64, ... (strided,
// coalesced 4B reads / 2B writes; same gate-weight pattern as verified round-5).
__global__ __launch_bounds__(256) void k_convert_gates(const float* __restrict__ x,
                                                       const float* __restrict__ Wg,
                                                       const float* __restrict__ Wgs,
                                                       unsigned short* __restrict__ x_bf,
                                                       float* __restrict__ g_all) {
    const int wv = threadIdx.x >> 6;
    const int lane = threadIdx.x & 63;
    const int b = blockIdx.x * 4 + wv;
    const float* xr = x + (size_t)b * D_SZ;
    unsigned short* xo = x_bf + (size_t)b * D_SZ;
    float acc[20];
#pragma unroll
    for (int j = 0; j < 20; ++j) acc[j] = 0.f;
#pragma unroll 4
    for (int it = 0; it < 16; ++it) {
        const int d = it * 64 + lane;
        const float xv = xr[d];
        xo[d] = f2bf(xv);
        const float* w0 = Wg + (size_t)d * 6;
        const float* w1 = Wg + (size_t)D_SZ * 6 + (size_t)d * 6;
        const float* ws = Wgs + (size_t)d * 8;
#pragma unroll
        for (int j = 0; j < 6; ++j) acc[j] += xv * w0[j];
#pragma unroll
        for (int j = 0; j < 6; ++j) acc[6 + j] += xv * w1[j];
#pragma unroll
        for (int j = 0; j < 8; ++j) acc[12 + j] += xv * ws[j];
    }
#pragma unroll
    for (int j = 0; j < 20; ++j) {
        float v = acc[j];
#pragma unroll
        for (int s = 32; s > 0; s >>= 1) v += __shfl_down(v, s, 64);
        acc[j] = v;
    }
    if (lane == 0) {
        float* g = g_all + (size_t)b * 20;
#pragma unroll
        for (int t = 0; t < 3; ++t) {
            int base = (t == 0) ? 0 : (t == 1 ? 6 : 12);
            int cnt  = (t == 2) ? 8 : 6;
            float m = -1e30f;
            for (int j = 0; j < cnt; ++j) m = fmaxf(m, acc[base + j]);
            float ex[8]; float sum = 0.f;
            for (int j = 0; j < cnt; ++j) { ex[j] = __expf(acc[base + j] - m); sum += ex[j]; }
            float inv = 1.f / sum;
            for (int j = 0; j < cnt; ++j) g[base + j] = ex[j] * inv;
        }
    }
}

// ------- transpose+convert: in [E][R][C] f32 -> out [E][C][R] bf16 -------
__global__ __launch_bounds__(512) void k_transpose_convert(const float* __restrict__ in,
                                                           unsigned short* __restrict__ out,
                                                           int R, int C) {
    __shared__ float tile[64][65];
    const float* src = in + (size_t)blockIdx.z * R * C;
    unsigned short* dst = out + (size_t)blockIdx.z * R * C;
    int c0 = blockIdx.x * 64, r0 = blockIdx.y * 64;
    int tx = threadIdx.x, ty = threadIdx.y;   // block (64,8)
#pragma unroll
    for (int rr = ty; rr < 64; rr += 8)
        tile[rr][tx] = src[(size_t)(r0 + rr) * C + c0 + tx];
    __syncthreads();
#pragma unroll
    for (int rr = ty; rr < 64; rr += 8)
        dst[(size_t)(c0 + rr) * R + r0 + tx] = f2bf(tile[tx][rr]);
}

// ---------------- 256x256 GEMM, 4 waves x 128x128/wave, BK=32, ring-4 ----------------
// C[M][N] = relu(A[M][K] * Bt[N][K]^T + bias), bf16 in/out, f32 accum.
// Geometry change vs rounds 3-6: square per-wave tile minimizes LDS-read bytes
// per FLOP ((Mw+Nw)/(Mw*Nw)); per-CU-tile ds_read drops 96 KiB -> 64 KiB.
// 256 threads = 4 waves (2M x 2N); per-wave acc[8][8] f32x4 (256 f32, AGPR),
// frag double-buffer 2x16 bf16x8. 1 wave/SIMD (LDS forces 1 block/CU anyway).
// Ring-4 pipeline (verified r3-5): stage t+3 during tile t; counted vmcnt
// (16 glds/stage; steady vmcnt(8) = allow stage(t+3) only); 1 barrier/tile.
// Swizzle (verified r3-5): physical 16B block = blk ^ ((row>>1)&3); linear
// glds dest + inverse-swizzled global source; 2-way (free) read aliasing.
__global__ __launch_bounds__(256, 1) void k_gemm4(
    const unsigned short* __restrict__ A,
    const unsigned short* __restrict__ Bt,
    const float* __restrict__ bias,
    unsigned short* __restrict__ C,
    int M, int N, int K,
    long long sA, long long sB, long long sBias, long long sC, int e_base) {

    const int tid = threadIdx.x;
    const int lane = tid & 63, wid = tid >> 6;
    const int wr = wid >> 1, wc = wid & 1;       // 2 x 2 wave grid
    const int lr = lane & 15, lg = lane >> 4;

    // bijective XCD swizzle on flat grid (nwg % 8 == 0 for all launches here)
    const int nwg = gridDim.x;
    const int wg = blockIdx.x;
    const int swz = (wg & 7) * (nwg >> 3) + (wg >> 3);
    const int nx = N >> 8;
    const int my = M >> 8;
    const int bx = swz % nx;
    const int t1 = swz / nx;
    const int by = t1 % my;
    const int e  = t1 / my + e_base;

    A    += (size_t)((long long)e * sA);
    Bt   += (size_t)((long long)e * sB);
    bias += (size_t)((long long)e * sBias);
    C    += (size_t)((long long)e * sC);

    const int m0 = by * 256, n0 = bx * 256;

    __shared__ __align__(16) unsigned short lds[65536];   // 128 KiB
    char* ldsb = (char*)lds;

    // staging: 256 thr x 16 B x 4 chunks per half (A 256x32 = 16 KiB), linear dest.
    // physical (row, blk) holds source col-block blk ^ ((row>>1)&3)
    const int srow = tid >> 2;                                // 0..63 (+64*chunk)
    const int scol = (((tid & 3) ^ ((tid >> 3) & 3)) * 8);    // inverse swizzle
    const int sdst = tid * 16;

    auto stage = [&](int t) {
        const int bb = (t & 3) * 32768;
        const unsigned short* a0 = A + (size_t)(m0 + srow) * K + (t << 5) + scol;
        const unsigned short* b0 = Bt + (size_t)(n0 + srow) * K + (t << 5) + scol;
#pragma unroll
        for (int r = 0; r < 4; ++r)
            __builtin_amdgcn_global_load_lds((gu32*)(a0 + (size_t)(r * 64) * K),
                                             (lu32*)(ldsb + bb + r * 4096 + sdst), 16, 0, 0);
#pragma unroll
        for (int r = 0; r < 4; ++r)
            __builtin_amdgcn_global_load_lds((gu32*)(b0 + (size_t)(r * 64) * K),
                                             (lu32*)(ldsb + bb + 16384 + r * 4096 + sdst), 16, 0, 0);
    };

    // fragment read constants (byte offsets); swizzle term depends only on lr
    const int cblk = (lg ^ ((lr >> 1) & 3)) * 16;
    const int aoff = wr * 8192 + lr * 64 + cblk;
    const int boff = 16384 + wc * 8192 + lr * 64 + cblk;

    // frags: f[0..7] = A rows (m-frags), f[8..15] = B cols (n-frags)
    auto loadf = [&](bf16x8* f, int bb) {
#pragma unroll
        for (int i = 0; i < 8; ++i)
            f[i] = *(const bf16x8*)(ldsb + bb + aoff + i * 1024);
#pragma unroll
        for (int j = 0; j < 8; ++j)
            f[8 + j] = *(const bf16x8*)(ldsb + bb + boff + j * 1024);
    };

    f32x4 acc[8][8];
#pragma unroll
    for (int i = 0; i < 8; ++i)
#pragma unroll
        for (int j = 0; j < 8; ++j)
            acc[i][j] = f32x4{0.f, 0.f, 0.f, 0.f};

    auto domfma = [&](const bf16x8* f) {
#pragma unroll
        for (int i = 0; i < 8; ++i)
#pragma unroll
            for (int j = 0; j < 8; ++j)
                acc[i][j] = __builtin_amdgcn_mfma_f32_16x16x32_bf16(f[i], f[8 + j], acc[i][j], 0, 0, 0);
    };

    const int NT = K >> 5;   // 32 (even, >= 8)

    // prologue: stage tiles 0,1,2 (24 glds); wait tiles 0,1 landed (leave tile2's 8)
    stage(0); stage(1); stage(2);
    asm volatile("s_waitcnt vmcnt(8)" ::: "memory");
    asm volatile("s_barrier" ::: "memory");

    bf16x8 fA[16], fB[16];
    loadf(fA, 0);

    for (int t = 0; t < NT; t += 2) {
        // ---- even tile t: consume fA(t); load fB(t+1); stage t+3 ----
        if (t + 3 < NT) stage(t + 3);
        loadf(fB, ((t + 1) & 3) * 32768);        // buf t+1 landed (prev boundary)
        domfma(fA);
        if (t + 3 < NT)      { asm volatile("s_waitcnt vmcnt(8)" ::: "memory"); }
        else if (t + 2 < NT) { asm volatile("s_waitcnt vmcnt(0)" ::: "memory"); }
        asm volatile("s_barrier" ::: "memory");

        // ---- odd tile t+1: consume fB(t+1); load fA(t+2); stage t+4 ----
        if (t + 4 < NT) stage(t + 4);
        if (t + 2 < NT) loadf(fA, ((t + 2) & 3) * 32768);
        domfma(fB);
        if (t + 4 < NT)      { asm volatile("s_waitcnt vmcnt(8)" ::: "memory"); }
        else if (t + 3 < NT) { asm volatile("s_waitcnt vmcnt(0)" ::: "memory"); }
        asm volatile("s_barrier" ::: "memory");
    }

    // ---- epilogue: bias + relu -> LDS-staged bf16 tile -> coalesced dwordx4 stores ----
    unsigned short* ct = (unsigned short*)ldsb;
#pragma unroll
    for (int j = 0; j < 8; ++j) {
        const int nn = wc * 128 + j * 16 + lr;
        const float bv = bias[n0 + nn];
#pragma unroll
        for (int i = 0; i < 8; ++i) {
            const int mb = wr * 128 + i * 16 + lg * 4;
#pragma unroll
            for (int r = 0; r < 4; ++r) {
                float v = fmaxf(acc[i][j][r] + bv, 0.f);
                ct[(size_t)(mb + r) * 256 + nn] = f2bf(v);
            }
        }
    }
    __syncthreads();
#pragma unroll
    for (int it = 0; it < 32; ++it) {
        const int row = it * 8 + (tid >> 5);
        const int colE = (tid & 31) * 8;
        *(int4*)(&C[(size_t)(m0 + row) * N + n0 + colE]) =
            *(const int4*)(ldsb + it * 4096 + (size_t)tid * 16);
    }
}

// ---------------- combine: out[b][t][o], 4 o's per thread ----------------
__global__ __launch_bounds__(256) void k_combine(const unsigned short* __restrict__ eo,
                                                 const float* __restrict__ g_all,
                                                 float* __restrict__ out) {
    int idx4 = blockIdx.x * 256 + threadIdx.x;    // over B*O/4
    int b = idx4 >> 7;                            // O/4 = 128
    int o4 = (idx4 & 127) * 4;
    const float* g = g_all + (size_t)b * 20;
    float v[E_SZ][4];
#pragma unroll
    for (int e = 0; e < E_SZ; ++e) {
        ushort4 u = *(const ushort4*)(eo + (size_t)e * B_SZ * O_SZ + (size_t)b * O_SZ + o4);
        v[e][0] = bf2f(u.x); v[e][1] = bf2f(u.y); v[e][2] = bf2f(u.z); v[e][3] = bf2f(u.w);
    }
    float4 r0, r1, r2;
    float* p0 = (float*)&r0; float* p1 = (float*)&r1; float* p2 = (float*)&r2;
#pragma unroll
    for (int c = 0; c < 4; ++c) {
        p0[c] = g[0] * v[0][c] + g[1] * v[1][c] + g[2] * v[4][c] + g[3] * v[5][c]
              + g[4] * v[6][c] + g[5] * v[7][c];
        p1[c] = g[6] * v[2][c] + g[7] * v[3][c] + g[8] * v[4][c] + g[9] * v[5][c]
              + g[10] * v[6][c] + g[11] * v[7][c];
        float s = 0.f;
#pragma unroll
        for (int e = 0; e < E_SZ; ++e) s += g[12 + e] * v[e][c];
        p2[c] = s;
    }
    size_t ob = (size_t)b * (3 * O_SZ) + o4;
    *(float4*)(out + ob) = r0;
    *(float4*)(out + ob + O_SZ) = r1;
    *(float4*)(out + ob + 2 * O_SZ) = r2;
}

extern "C" void kernel_launch(void* const* d_in, const int* in_sizes, int n_in,
                              void* d_out, int out_size, void* d_ws, size_t ws_size,
                              hipStream_t stream) {
    const float* x   = (const float*)d_in[0];
    const float* W1  = (const float*)d_in[1];
    const float* b1  = (const float*)d_in[2];
    const float* W2  = (const float*)d_in[3];
    const float* b2  = (const float*)d_in[4];
    const float* Wg  = (const float*)d_in[5];
    const float* Wgs = (const float*)d_in[6];
    float* out = (float*)d_out;

    char* ws = (char*)d_ws;
    const size_t SZ_XBF  = (size_t)B_SZ * D_SZ * 2;           // 16 MB
    const size_t SZ_W1T  = (size_t)E_SZ * H_SZ * D_SZ * 2;    // 16 MB
    const size_t SZ_W2T  = (size_t)E_SZ * O_SZ * H_SZ * 2;    // 8 MB
    const size_t SZ_EO   = (size_t)E_SZ * B_SZ * O_SZ * 2;    // 64 MB
    const size_t SZ_G    = (size_t)B_SZ * 20 * 4;             // 640 KB
    const size_t SZ_HBIG = (size_t)E_SZ * B_SZ * H_SZ * 2;    // 128 MB

    unsigned short* x_bf = (unsigned short*)ws;              ws += SZ_XBF;
    unsigned short* W1T  = (unsigned short*)ws;              ws += SZ_W1T;
    unsigned short* W2T  = (unsigned short*)ws;              ws += SZ_W2T;
    unsigned short* eo   = (unsigned short*)ws;              ws += SZ_EO;
    float* g_all         = (float*)ws;                       ws += SZ_G;
    unsigned short* h_buf = (unsigned short*)ws;

    const size_t fixed = SZ_XBF + SZ_W1T + SZ_W2T + SZ_EO + SZ_G;
    const bool big = ws_size >= fixed + SZ_HBIG;

    // 1) fused convert + gates; weight transposes
    k_convert_gates<<<B_SZ / 4, 256, 0, stream>>>(x, Wg, Wgs, x_bf, g_all);
    dim3 tb(64, 8);
    k_transpose_convert<<<dim3(H_SZ / 64, D_SZ / 64, E_SZ), tb, 0, stream>>>(W1, W1T, D_SZ, H_SZ);
    k_transpose_convert<<<dim3(O_SZ / 64, H_SZ / 64, E_SZ), tb, 0, stream>>>(W2, W2T, H_SZ, O_SZ);

    // 2) expert GEMMs (256x256 tiles; flat 1D grids, all % 8 == 0)
    if (big) {
        k_gemm4<<<(H_SZ / 256) * (B_SZ / 256) * E_SZ, 256, 0, stream>>>(
            x_bf, W1T, b1, h_buf, B_SZ, H_SZ, D_SZ,
            0LL, (long long)H_SZ * D_SZ, (long long)H_SZ, (long long)B_SZ * H_SZ, 0);
        k_gemm4<<<(O_SZ / 256) * (B_SZ / 256) * E_SZ, 256, 0, stream>>>(
            h_buf, W2T, b2, eo, B_SZ, O_SZ, H_SZ,
            (long long)B_SZ * H_SZ, (long long)O_SZ * H_SZ, (long long)O_SZ, (long long)B_SZ * O_SZ, 0);
    } else {
        for (int e = 0; e < E_SZ; ++e) {
            k_gemm4<<<(H_SZ / 256) * (B_SZ / 256), 256, 0, stream>>>(
                x_bf, W1T, b1, h_buf, B_SZ, H_SZ, D_SZ,
                0LL, (long long)H_SZ * D_SZ, (long long)H_SZ, 0LL, e);
            k_gemm4<<<(O_SZ / 256) * (B_SZ / 256), 256, 0, stream>>>(
                h_buf, W2T, b2, eo, B_SZ, O_SZ, H_SZ,
                0LL, (long long)O_SZ * H_SZ, (long long)O_SZ, (long long)B_SZ * O_SZ, e);
        }
    }

    // 3) combine
    k_combine<<<(B_SZ * O_SZ / 4) / 256, 256, 0, stream>>>(eo, g_all, out);
}

// Round 8
// 312.535 us; speedup vs baseline: 1.2900x; 1.2900x over previous
//
#include <hip/hip_runtime.h>
#include <hip/hip_bf16.h>
#include <stdint.h>

#define B_SZ 8192
#define D_SZ 1024
#define H_SZ 1024
#define O_SZ 512
#define E_SZ 8

typedef float f32x4 __attribute__((ext_vector_type(4)));
typedef __bf16 bf16x8 __attribute__((ext_vector_type(8)));

typedef __attribute__((address_space(1))) uint32_t gu32;
typedef __attribute__((address_space(3))) uint32_t lu32;

__device__ __forceinline__ unsigned short f2bf(float f) {
    union { __hip_bfloat16 h; unsigned short u; } c;
    c.h = __float2bfloat16(f);
    return c.u;
}
__device__ __forceinline__ float bf2f(unsigned short u) {
    union { float f; uint32_t u; } c;
    c.u = ((uint32_t)u) << 16;
    return c.f;
}

// ------- fused: convert x row to bf16 AND 20 gate logits + 3 softmaxes -------
// 4 waves/block, one x-row per wave; lane-strided (verified round-5/7 pattern).
__global__ __launch_bounds__(256) void k_convert_gates(const float* __restrict__ x,
                                                       const float* __restrict__ Wg,
                                                       const float* __restrict__ Wgs,
                                                       unsigned short* __restrict__ x_bf,
                                                       float* __restrict__ g_all) {
    const int wv = threadIdx.x >> 6;
    const int lane = threadIdx.x & 63;
    const int b = blockIdx.x * 4 + wv;
    const float* xr = x + (size_t)b * D_SZ;
    unsigned short* xo = x_bf + (size_t)b * D_SZ;
    float acc[20];
#pragma unroll
    for (int j = 0; j < 20; ++j) acc[j] = 0.f;
#pragma unroll 4
    for (int it = 0; it < 16; ++it) {
        const int d = it * 64 + lane;
        const float xv = xr[d];
        xo[d] = f2bf(xv);
        const float* w0 = Wg + (size_t)d * 6;
        const float* w1 = Wg + (size_t)D_SZ * 6 + (size_t)d * 6;
        const float* ws = Wgs + (size_t)d * 8;
#pragma unroll
        for (int j = 0; j < 6; ++j) acc[j] += xv * w0[j];
#pragma unroll
        for (int j = 0; j < 6; ++j) acc[6 + j] += xv * w1[j];
#pragma unroll
        for (int j = 0; j < 8; ++j) acc[12 + j] += xv * ws[j];
    }
#pragma unroll
    for (int j = 0; j < 20; ++j) {
        float v = acc[j];
#pragma unroll
        for (int s = 32; s > 0; s >>= 1) v += __shfl_down(v, s, 64);
        acc[j] = v;
    }
    if (lane == 0) {
        float* g = g_all + (size_t)b * 20;
#pragma unroll
        for (int t = 0; t < 3; ++t) {
            int base = (t == 0) ? 0 : (t == 1 ? 6 : 12);
            int cnt  = (t == 2) ? 8 : 6;
            float m = -1e30f;
            for (int j = 0; j < cnt; ++j) m = fmaxf(m, acc[base + j]);
            float ex[8]; float sum = 0.f;
            for (int j = 0; j < cnt; ++j) { ex[j] = __expf(acc[base + j] - m); sum += ex[j]; }
            float inv = 1.f / sum;
            for (int j = 0; j < cnt; ++j) g[base + j] = ex[j] * inv;
        }
    }
}

// ------- transpose+convert: in [E][R][C] f32 -> out [E][C][R] bf16 -------
__global__ __launch_bounds__(512) void k_transpose_convert(const float* __restrict__ in,
                                                           unsigned short* __restrict__ out,
                                                           int R, int C) {
    __shared__ float tile[64][65];
    const float* src = in + (size_t)blockIdx.z * R * C;
    unsigned short* dst = out + (size_t)blockIdx.z * R * C;
    int c0 = blockIdx.x * 64, r0 = blockIdx.y * 64;
    int tx = threadIdx.x, ty = threadIdx.y;   // block (64,8)
#pragma unroll
    for (int rr = ty; rr < 64; rr += 8)
        tile[rr][tx] = src[(size_t)(r0 + rr) * C + c0 + tx];
    __syncthreads();
#pragma unroll
    for (int rr = ty; rr < 64; rr += 8)
        dst[(size_t)(c0 + rr) * R + r0 + tx] = f2bf(tile[tx][rr]);
}

// ------- 256x256 bf16 GEMM: ring-4 BK=32 buffers + m201-style 2-phase/tile fine interleave -------
// C[M][N] = relu(A[M][K] * Bt[N][K]^T + bias), bf16 in/out, f32 accum.
// 512 threads = 8 waves (2M x 4N); per-wave 128x64 out, acc[8][4] f32x4.
// LDS 128 KiB = 4 round-robin K-tile buffers x 32 KiB { A 256x32, B 256x32 }.
// Per tile, 2 phases (m201 recipe texture):
//   phase A: 8 ds_read_b128 (fa0-3,fb0-3) + 2 glds (A halves of t+3) | bar | prio1 | 16 MFMA | prio0 | bar
//   phase B: 4 ds_read_b128 (fa4-7)       + 2 glds (B halves of t+3) | bar | prio1 | 16 MFMA | prio0 | vmcnt | bar
// Race-free invariant (r3-5 verified): stage target (t+3)%4 never in readable set {t,t+1,t+2}.
// Counted vmcnt: end of tile t leaves {t+2,t+3} stages (8 loads) in flight -> vmcnt(8); tail 4, 0.
// Swizzle (r3-5 verified): physical 16B block = blk ^ ((row>>1)&3); linear glds dest +
// inverse-swizzled global source; 2-way (free) read aliasing.
__global__ __launch_bounds__(512, 2) void k_gemm8p(
    const unsigned short* __restrict__ A,
    const unsigned short* __restrict__ Bt,
    const float* __restrict__ bias,
    unsigned short* __restrict__ C,
    int M, int N, int K,
    long long sA, long long sB, long long sBias, long long sC, int e_base) {

    const int tid = threadIdx.x;
    const int lane = tid & 63, wid = tid >> 6;
    const int wr = wid >> 2, wc = wid & 3;       // 2 x 4 wave grid
    const int lr = lane & 15, lg = lane >> 4;

    // bijective XCD swizzle on flat grid (nwg % 8 == 0 for all launches here)
    const int nwg = gridDim.x;
    const int wg = blockIdx.x;
    const int swz = (wg & 7) * (nwg >> 3) + (wg >> 3);
    const int nx = N >> 8;
    const int my = M >> 8;
    const int bx = swz % nx;
    const int t1 = swz / nx;
    const int by = t1 % my;
    const int e  = t1 / my + e_base;

    A    += (size_t)((long long)e * sA);
    Bt   += (size_t)((long long)e * sB);
    bias += (size_t)((long long)e * sBias);
    C    += (size_t)((long long)e * sC);

    const int m0 = by * 256, n0 = bx * 256;

    __shared__ __align__(16) unsigned short lds[65536];   // 128 KiB
    char* ldsb = (char*)lds;

    // staging: 512 thr x 16 B = one 8 KiB half (128 rows x 32 cols bf16), linear dest.
    // physical (row, blk) holds source col-block blk ^ ((row>>1)&3)  (blk = 8-elem group)
    const int srow = tid >> 2;
    const int scol = (((tid & 3) ^ ((tid >> 3) & 3)) * 8);
    const int sdst = tid * 16;

    auto stageA2 = [&](int t) {   // A halves (chunks 0,1)
        const int bb = (t & 3) * 32768;
        const unsigned short* s0 = A + (size_t)(m0 + srow) * K + (t << 5) + scol;
        __builtin_amdgcn_global_load_lds((gu32*)s0, (lu32*)(ldsb + bb + sdst), 16, 0, 0);
        __builtin_amdgcn_global_load_lds((gu32*)(s0 + (size_t)128 * K),
                                         (lu32*)(ldsb + bb + 8192 + sdst), 16, 0, 0);
    };
    auto stageB2 = [&](int t) {   // B halves (chunks 2,3)
        const int bb = (t & 3) * 32768 + 16384;
        const unsigned short* s0 = Bt + (size_t)(n0 + srow) * K + (t << 5) + scol;
        __builtin_amdgcn_global_load_lds((gu32*)s0, (lu32*)(ldsb + bb + sdst), 16, 0, 0);
        __builtin_amdgcn_global_load_lds((gu32*)(s0 + (size_t)128 * K),
                                         (lu32*)(ldsb + bb + 8192 + sdst), 16, 0, 0);
    };

    // fragment read constants (byte offsets); swizzle term depends only on lr
    const int cblk = (lg ^ ((lr >> 1) & 3)) * 16;
    const int aoff = wr * 8192 + lr * 64 + cblk;
    const int boff = 16384 + (wc >> 1) * 8192 + (wc & 1) * 4096 + lr * 64 + cblk;

    f32x4 acc[8][4];
#pragma unroll
    for (int i = 0; i < 8; ++i)
#pragma unroll
        for (int j = 0; j < 4; ++j)
            acc[i][j] = f32x4{0.f, 0.f, 0.f, 0.f};

    const int NT = K >> 5;   // 32

    // prologue: stage tiles 0,1,2 (12 glds); vmcnt(8) -> tile 0 landed
    stageA2(0); stageB2(0); stageA2(1); stageB2(1); stageA2(2); stageB2(2);
    asm volatile("s_waitcnt vmcnt(8)" ::: "memory");
    asm volatile("s_barrier" ::: "memory");

    for (int t = 0; t < NT; ++t) {
        const int bb = (t & 3) * 32768;
        const bool st = (t + 3 < NT);
        bf16x8 fa[4], fb[4];

        // ---- phase A: reads fa0-3, fb0-3; stage A-halves of t+3; MFMA upper output half ----
#pragma unroll
        for (int i = 0; i < 4; ++i)
            fa[i] = *(const bf16x8*)(ldsb + bb + aoff + i * 1024);
#pragma unroll
        for (int j = 0; j < 4; ++j)
            fb[j] = *(const bf16x8*)(ldsb + bb + boff + j * 1024);
        if (st) stageA2(t + 3);
        asm volatile("s_barrier" ::: "memory");
        __builtin_amdgcn_s_setprio(1);
#pragma unroll
        for (int i = 0; i < 4; ++i)
#pragma unroll
            for (int j = 0; j < 4; ++j)
                acc[i][j] = __builtin_amdgcn_mfma_f32_16x16x32_bf16(fa[i], fb[j], acc[i][j], 0, 0, 0);
        __builtin_amdgcn_s_setprio(0);
        asm volatile("s_barrier" ::: "memory");

        // ---- phase B: reads fa4-7; stage B-halves of t+3; MFMA lower output half (fb held) ----
        bf16x8 ga[4];
#pragma unroll
        for (int i = 0; i < 4; ++i)
            ga[i] = *(const bf16x8*)(ldsb + bb + aoff + (4 + i) * 1024);
        if (st) stageB2(t + 3);
        asm volatile("s_barrier" ::: "memory");
        __builtin_amdgcn_s_setprio(1);
#pragma unroll
        for (int i = 0; i < 4; ++i)
#pragma unroll
            for (int j = 0; j < 4; ++j)
                acc[4 + i][j] = __builtin_amdgcn_mfma_f32_16x16x32_bf16(ga[i], fb[j], acc[4 + i][j], 0, 0, 0);
        __builtin_amdgcn_s_setprio(0);
        // boundary (counted, never drains in steady state): ensure tile t+1 landed
        if (t < NT - 3)       { asm volatile("s_waitcnt vmcnt(8)" ::: "memory"); }
        else if (t == NT - 3) { asm volatile("s_waitcnt vmcnt(4)" ::: "memory"); }
        else if (t == NT - 2) { asm volatile("s_waitcnt vmcnt(0)" ::: "memory"); }
        asm volatile("s_barrier" ::: "memory");
    }

    // ---- epilogue: bias + relu -> LDS-staged bf16 tile -> coalesced dwordx4 stores ----
    unsigned short* ct = (unsigned short*)ldsb;
#pragma unroll
    for (int j = 0; j < 4; ++j) {
        const int nn = wc * 64 + j * 16 + lr;
        const float bv = bias[n0 + nn];
#pragma unroll
        for (int i = 0; i < 8; ++i) {
            const int mb = wr * 128 + i * 16 + lg * 4;
#pragma unroll
            for (int r = 0; r < 4; ++r) {
                float v = fmaxf(acc[i][j][r] + bv, 0.f);
                ct[(size_t)(mb + r) * 256 + nn] = f2bf(v);
            }
        }
    }
    __syncthreads();
#pragma unroll
    for (int it = 0; it < 16; ++it) {
        const int row = it * 16 + (tid >> 5);
        const int colE = (tid & 31) * 8;
        *(int4*)(&C[(size_t)(m0 + row) * N + n0 + colE]) =
            *(const int4*)(ldsb + it * 8192 + (size_t)tid * 16);
    }
}

// ---------------- combine: out[b][t][o], 4 o's per thread ----------------
__global__ __launch_bounds__(256) void k_combine(const unsigned short* __restrict__ eo,
                                                 const float* __restrict__ g_all,
                                                 float* __restrict__ out) {
    int idx4 = blockIdx.x * 256 + threadIdx.x;    // over B*O/4
    int b = idx4 >> 7;                            // O/4 = 128
    int o4 = (idx4 & 127) * 4;
    const float* g = g_all + (size_t)b * 20;
    float v[E_SZ][4];
#pragma unroll
    for (int e = 0; e < E_SZ; ++e) {
        ushort4 u = *(const ushort4*)(eo + (size_t)e * B_SZ * O_SZ + (size_t)b * O_SZ + o4);
        v[e][0] = bf2f(u.x); v[e][1] = bf2f(u.y); v[e][2] = bf2f(u.z); v[e][3] = bf2f(u.w);
    }
    float4 r0, r1, r2;
    float* p0 = (float*)&r0; float* p1 = (float*)&r1; float* p2 = (float*)&r2;
#pragma unroll
    for (int c = 0; c < 4; ++c) {
        p0[c] = g[0] * v[0][c] + g[1] * v[1][c] + g[2] * v[4][c] + g[3] * v[5][c]
              + g[4] * v[6][c] + g[5] * v[7][c];
        p1[c] = g[6] * v[2][c] + g[7] * v[3][c] + g[8] * v[4][c] + g[9] * v[5][c]
              + g[10] * v[6][c] + g[11] * v[7][c];
        float s = 0.f;
#pragma unroll
        for (int e = 0; e < E_SZ; ++e) s += g[12 + e] * v[e][c];
        p2[c] = s;
    }
    size_t ob = (size_t)b * (3 * O_SZ) + o4;
    *(float4*)(out + ob) = r0;
    *(float4*)(out + ob + O_SZ) = r1;
    *(float4*)(out + ob + 2 * O_SZ) = r2;
}

extern "C" void kernel_launch(void* const* d_in, const int* in_sizes, int n_in,
                              void* d_out, int out_size, void* d_ws, size_t ws_size,
                              hipStream_t stream) {
    const float* x   = (const float*)d_in[0];
    const float* W1  = (const float*)d_in[1];
    const float* b1  = (const float*)d_in[2];
    const float* W2  = (const float*)d_in[3];
    const float* b2  = (const float*)d_in[4];
    const float* Wg  = (const float*)d_in[5];
    const float* Wgs = (const float*)d_in[6];
    float* out = (float*)d_out;

    char* ws = (char*)d_ws;
    const size_t SZ_XBF  = (size_t)B_SZ * D_SZ * 2;           // 16 MB
    const size_t SZ_W1T  = (size_t)E_SZ * H_SZ * D_SZ * 2;    // 16 MB
    const size_t SZ_W2T  = (size_t)E_SZ * O_SZ * H_SZ * 2;    // 8 MB
    const size_t SZ_EO   = (size_t)E_SZ * B_SZ * O_SZ * 2;    // 64 MB
    const size_t SZ_G    = (size_t)B_SZ * 20 * 4;             // 640 KB
    const size_t SZ_HBIG = (size_t)E_SZ * B_SZ * H_SZ * 2;    // 128 MB

    unsigned short* x_bf = (unsigned short*)ws;              ws += SZ_XBF;
    unsigned short* W1T  = (unsigned short*)ws;              ws += SZ_W1T;
    unsigned short* W2T  = (unsigned short*)ws;              ws += SZ_W2T;
    unsigned short* eo   = (unsigned short*)ws;              ws += SZ_EO;
    float* g_all         = (float*)ws;                       ws += SZ_G;
    unsigned short* h_buf = (unsigned short*)ws;

    const size_t fixed = SZ_XBF + SZ_W1T + SZ_W2T + SZ_EO + SZ_G;
    const bool big = ws_size >= fixed + SZ_HBIG;

    // 1) fused convert + gates; weight transposes
    k_convert_gates<<<B_SZ / 4, 256, 0, stream>>>(x, Wg, Wgs, x_bf, g_all);
    dim3 tb(64, 8);
    k_transpose_convert<<<dim3(H_SZ / 64, D_SZ / 64, E_SZ), tb, 0, stream>>>(W1, W1T, D_SZ, H_SZ);
    k_transpose_convert<<<dim3(O_SZ / 64, H_SZ / 64, E_SZ), tb, 0, stream>>>(W2, W2T, H_SZ, O_SZ);

    // 2) expert GEMMs (256x256 tiles; flat 1D grids, all % 8 == 0)
    if (big) {
        k_gemm8p<<<(H_SZ / 256) * (B_SZ / 256) * E_SZ, 512, 0, stream>>>(
            x_bf, W1T, b1, h_buf, B_SZ, H_SZ, D_SZ,
            0LL, (long long)H_SZ * D_SZ, (long long)H_SZ, (long long)B_SZ * H_SZ, 0);
        k_gemm8p<<<(O_SZ / 256) * (B_SZ / 256) * E_SZ, 512, 0, stream>>>(
            h_buf, W2T, b2, eo, B_SZ, O_SZ, H_SZ,
            (long long)B_SZ * H_SZ, (long long)O_SZ * H_SZ, (long long)O_SZ, (long long)B_SZ * O_SZ, 0);
    } else {
        for (int e = 0; e < E_SZ; ++e) {
            k_gemm8p<<<(H_SZ / 256) * (B_SZ / 256), 512, 0, stream>>>(
                x_bf, W1T, b1, h_buf, B_SZ, H_SZ, D_SZ,
                0LL, (long long)H_SZ * D_SZ, (long long)H_SZ, 0LL, e);
            k_gemm8p<<<(O_SZ / 256) * (B_SZ / 256), 512, 0, stream>>>(
                h_buf, W2T, b2, eo, B_SZ, O_SZ, H_SZ,
                0LL, (long long)O_SZ * H_SZ, (long long)O_SZ, (long long)B_SZ * O_SZ, e);
        }
    }

    // 3) combine
    k_combine<<<(B_SZ * O_SZ / 4) / 256, 256, 0, stream>>>(eo, g_all, out);
}

// Round 9
// 307.009 us; speedup vs baseline: 1.3132x; 1.0180x over previous
//
#include <hip/hip_runtime.h>
#include <hip/hip_bf16.h>
#include <stdint.h>

#define B_SZ 8192
#define D_SZ 1024
#define H_SZ 1024
#define O_SZ 512
#define E_SZ 8

typedef float f32x4 __attribute__((ext_vector_type(4)));
typedef __bf16 bf16x8 __attribute__((ext_vector_type(8)));

typedef __attribute__((address_space(1))) uint32_t gu32;
typedef __attribute__((address_space(3))) uint32_t lu32;

__device__ __forceinline__ unsigned short f2bf(float f) {
    union { __hip_bfloat16 h; unsigned short u; } c;
    c.h = __float2bfloat16(f);
    return c.u;
}
__device__ __forceinline__ float bf2f(unsigned short u) {
    union { float f; uint32_t u; } c;
    c.u = ((uint32_t)u) << 16;
    return c.f;
}

// ------- fused: convert x row to bf16 AND 20 gate logits + 3 softmaxes -------
__global__ __launch_bounds__(256) void k_convert_gates(const float* __restrict__ x,
                                                       const float* __restrict__ Wg,
                                                       const float* __restrict__ Wgs,
                                                       unsigned short* __restrict__ x_bf,
                                                       float* __restrict__ g_all) {
    const int wv = threadIdx.x >> 6;
    const int lane = threadIdx.x & 63;
    const int b = blockIdx.x * 4 + wv;
    const float* xr = x + (size_t)b * D_SZ;
    unsigned short* xo = x_bf + (size_t)b * D_SZ;
    float acc[20];
#pragma unroll
    for (int j = 0; j < 20; ++j) acc[j] = 0.f;
#pragma unroll 4
    for (int it = 0; it < 16; ++it) {
        const int d = it * 64 + lane;
        const float xv = xr[d];
        xo[d] = f2bf(xv);
        const float* w0 = Wg + (size_t)d * 6;
        const float* w1 = Wg + (size_t)D_SZ * 6 + (size_t)d * 6;
        const float* ws = Wgs + (size_t)d * 8;
#pragma unroll
        for (int j = 0; j < 6; ++j) acc[j] += xv * w0[j];
#pragma unroll
        for (int j = 0; j < 6; ++j) acc[6 + j] += xv * w1[j];
#pragma unroll
        for (int j = 0; j < 8; ++j) acc[12 + j] += xv * ws[j];
    }
#pragma unroll
    for (int j = 0; j < 20; ++j) {
        float v = acc[j];
#pragma unroll
        for (int s = 32; s > 0; s >>= 1) v += __shfl_down(v, s, 64);
        acc[j] = v;
    }
    if (lane == 0) {
        float* g = g_all + (size_t)b * 20;
#pragma unroll
        for (int t = 0; t < 3; ++t) {
            int base = (t == 0) ? 0 : (t == 1 ? 6 : 12);
            int cnt  = (t == 2) ? 8 : 6;
            float m = -1e30f;
            for (int j = 0; j < cnt; ++j) m = fmaxf(m, acc[base + j]);
            float ex[8]; float sum = 0.f;
            for (int j = 0; j < cnt; ++j) { ex[j] = __expf(acc[base + j] - m); sum += ex[j]; }
            float inv = 1.f / sum;
            for (int j = 0; j < cnt; ++j) g[base + j] = ex[j] * inv;
        }
    }
}

// ------- transpose+convert: in [E][R][C] f32 -> out [E][C][R] bf16 -------
__global__ __launch_bounds__(512) void k_transpose_convert(const float* __restrict__ in,
                                                           unsigned short* __restrict__ out,
                                                           int R, int C) {
    __shared__ float tile[64][65];
    const float* src = in + (size_t)blockIdx.z * R * C;
    unsigned short* dst = out + (size_t)blockIdx.z * R * C;
    int c0 = blockIdx.x * 64, r0 = blockIdx.y * 64;
    int tx = threadIdx.x, ty = threadIdx.y;   // block (64,8)
#pragma unroll
    for (int rr = ty; rr < 64; rr += 8)
        tile[rr][tx] = src[(size_t)(r0 + rr) * C + c0 + tx];
    __syncthreads();
#pragma unroll
    for (int rr = ty; rr < 64; rr += 8)
        dst[(size_t)(c0 + rr) * R + r0 + tx] = f2bf(tile[tx][rr]);
}

// ------- 256x256 bf16 GEMM: ring-4 BK=32 + ONE-PHASE-AHEAD fragment pipeline -------
// C[M][N] = relu(A[M][K] * Bt[N][K]^T + bias), bf16 in/out, f32 accum.
// 512 thr = 8 waves (2M x 4N); per-wave 128x64 out, acc[8][4] f32x4.
// LDS 128 KiB = 4 ring K-tile buffers x 32 KiB { A 256x32, B 256x32 }.
// KEY CHANGE vs r8: each phase's ds_reads feed the NEXT phase's MFMA, so the
// lgkm wait before every MFMA cluster covers reads issued a full phase earlier
// (hidden under the previous MFMA). Phase = {reads(next) ; vmcnt ; barrier ;
// stage(post-barrier) ; prio1 ; 16 MFMA(prev reads) ; prio0}.
// Ordering proofs:
//  RAW: reads of buf t+1 come after a barrier preceded by every wave's vmcnt(4)
//       (the 4 loads younger than Bh(t+1)) -> t+1 globally landed. Tail vmcnt(0).
//  WAR: stage(t+4) (rewrites buf t%4) is POST-barrier; every wave reaches that
//       barrier only after its buf-t reads were lgkm-drained by the consuming MFMA.
// Swizzle (r3-8 verified): phys 16B block = blk ^ ((row>>1)&3); linear glds dest
// + inverse-swizzled source; 2-way (free) read aliasing.
__global__ __launch_bounds__(512, 2) void k_gemm_pipe(
    const unsigned short* __restrict__ A,
    const unsigned short* __restrict__ Bt,
    const float* __restrict__ bias,
    unsigned short* __restrict__ C,
    int M, int N, int K,
    long long sA, long long sB, long long sBias, long long sC, int e_base) {

    const int tid = threadIdx.x;
    const int lane = tid & 63, wid = tid >> 6;
    const int wr = wid >> 2, wc = wid & 3;       // 2 x 4 wave grid
    const int lr = lane & 15, lg = lane >> 4;

    // bijective XCD swizzle on flat grid (nwg % 8 == 0 for all launches here)
    const int nwg = gridDim.x;
    const int wg = blockIdx.x;
    const int swz = (wg & 7) * (nwg >> 3) + (wg >> 3);
    const int nx = N >> 8;
    const int my = M >> 8;
    const int bx = swz % nx;
    const int t1 = swz / nx;
    const int by = t1 % my;
    const int e  = t1 / my + e_base;

    A    += (size_t)((long long)e * sA);
    Bt   += (size_t)((long long)e * sB);
    bias += (size_t)((long long)e * sBias);
    C    += (size_t)((long long)e * sC);

    const int m0 = by * 256, n0 = bx * 256;

    __shared__ __align__(16) unsigned short lds[65536];   // 128 KiB
    char* ldsb = (char*)lds;

    // staging: 512 thr x 16 B = one 8 KiB half (128 rows x 32 cols bf16), linear dest.
    const int srow = tid >> 2;
    const int scol = (((tid & 3) ^ ((tid >> 3) & 3)) * 8);
    const int sdst = tid * 16;

    auto stageA2 = [&](int t) {   // A halves
        const int bb = (t & 3) * 32768;
        const unsigned short* s0 = A + (size_t)(m0 + srow) * K + (t << 5) + scol;
        __builtin_amdgcn_global_load_lds((gu32*)s0, (lu32*)(ldsb + bb + sdst), 16, 0, 0);
        __builtin_amdgcn_global_load_lds((gu32*)(s0 + (size_t)128 * K),
                                         (lu32*)(ldsb + bb + 8192 + sdst), 16, 0, 0);
    };
    auto stageB2 = [&](int t) {   // B halves
        const int bb = (t & 3) * 32768 + 16384;
        const unsigned short* s0 = Bt + (size_t)(n0 + srow) * K + (t << 5) + scol;
        __builtin_amdgcn_global_load_lds((gu32*)s0, (lu32*)(ldsb + bb + sdst), 16, 0, 0);
        __builtin_amdgcn_global_load_lds((gu32*)(s0 + (size_t)128 * K),
                                         (lu32*)(ldsb + bb + 8192 + sdst), 16, 0, 0);
    };

    // fragment read constants (byte offsets); swizzle term depends only on lr
    const int cblk = (lg ^ ((lr >> 1) & 3)) * 16;
    const int aoff = wr * 8192 + lr * 64 + cblk;
    const int boff = 16384 + (wc >> 1) * 8192 + (wc & 1) * 4096 + lr * 64 + cblk;

    f32x4 acc[8][4];
#pragma unroll
    for (int i = 0; i < 8; ++i)
#pragma unroll
        for (int j = 0; j < 4; ++j)
            acc[i][j] = f32x4{0.f, 0.f, 0.f, 0.f};

    auto mfma16 = [&](const bf16x8 (&fa)[4], const bf16x8 (&fb)[4], int rbase) {
        __builtin_amdgcn_s_setprio(1);
#pragma unroll
        for (int i = 0; i < 4; ++i)
#pragma unroll
            for (int j = 0; j < 4; ++j)
                acc[rbase + i][j] = __builtin_amdgcn_mfma_f32_16x16x32_bf16(
                    fa[i], fb[j], acc[rbase + i][j], 0, 0, 0);
        __builtin_amdgcn_s_setprio(0);
    };

    const int NT = K >> 5;   // 32 (even)

    // prologue: stage tiles 0,1,2 (12 glds); vmcnt(8) -> tile 0 landed; read tile-0 U frags
    stageA2(0); stageB2(0); stageA2(1); stageB2(1); stageA2(2); stageB2(2);
    asm volatile("s_waitcnt vmcnt(8)" ::: "memory");
    asm volatile("s_barrier" ::: "memory");

    bf16x8 aU0[4], aL0[4], b0[4], aU1[4], aL1[4], b1v[4];
#pragma unroll
    for (int i = 0; i < 4; ++i) aU0[i] = *(const bf16x8*)(ldsb + aoff + i * 1024);
#pragma unroll
    for (int j = 0; j < 4; ++j) b0[j]  = *(const bf16x8*)(ldsb + boff + j * 1024);

    for (int t = 0; t < NT; t += 2) {
        const int bb0 = (t & 3) * 32768;
        const int bb1 = ((t + 1) & 3) * 32768;
        const int bb2 = ((t + 2) & 3) * 32768;

        // ---- phase (t,U): read L-frags(t); ensure t+1 landed; MFMA U(t) ----
#pragma unroll
        for (int i = 0; i < 4; ++i) aL0[i] = *(const bf16x8*)(ldsb + bb0 + aoff + (4 + i) * 1024);
        if (t + 2 < NT) { asm volatile("s_waitcnt vmcnt(4)" ::: "memory"); }
        else            { asm volatile("s_waitcnt vmcnt(0)" ::: "memory"); }
        asm volatile("s_barrier" ::: "memory");
        if (t + 3 < NT) stageA2(t + 3);
        mfma16(aU0, b0, 0);

        // ---- phase (t,L): read U-frags(t+1); MFMA L(t) ----
#pragma unroll
        for (int i = 0; i < 4; ++i) aU1[i] = *(const bf16x8*)(ldsb + bb1 + aoff + i * 1024);
#pragma unroll
        for (int j = 0; j < 4; ++j) b1v[j] = *(const bf16x8*)(ldsb + bb1 + boff + j * 1024);
        asm volatile("s_barrier" ::: "memory");
        if (t + 3 < NT) stageB2(t + 3);
        mfma16(aL0, b0, 4);

        // ---- phase (t+1,U): read L-frags(t+1); ensure t+2 landed; MFMA U(t+1) ----
#pragma unroll
        for (int i = 0; i < 4; ++i) aL1[i] = *(const bf16x8*)(ldsb + bb1 + aoff + (4 + i) * 1024);
        if (t + 3 < NT) { asm volatile("s_waitcnt vmcnt(4)" ::: "memory"); }
        else            { asm volatile("s_waitcnt vmcnt(0)" ::: "memory"); }
        asm volatile("s_barrier" ::: "memory");
        if (t + 4 < NT) stageA2(t + 4);
        mfma16(aU1, b1v, 0);

        // ---- phase (t+1,L): read U-frags(t+2); MFMA L(t+1) ----
        if (t + 2 < NT) {
#pragma unroll
            for (int i = 0; i < 4; ++i) aU0[i] = *(const bf16x8*)(ldsb + bb2 + aoff + i * 1024);
#pragma unroll
            for (int j = 0; j < 4; ++j) b0[j]  = *(const bf16x8*)(ldsb + bb2 + boff + j * 1024);
        }
        asm volatile("s_barrier" ::: "memory");
        if (t + 4 < NT) stageB2(t + 4);
        mfma16(aL1, b1v, 4);
    }

    // ---- epilogue: full drain, then bias+relu -> LDS tile -> coalesced stores ----
    __syncthreads();
    unsigned short* ct = (unsigned short*)ldsb;
#pragma unroll
    for (int j = 0; j < 4; ++j) {
        const int nn = wc * 64 + j * 16 + lr;
        const float bv = bias[n0 + nn];
#pragma unroll
        for (int i = 0; i < 8; ++i) {
            const int mb = wr * 128 + i * 16 + lg * 4;
#pragma unroll
            for (int r = 0; r < 4; ++r) {
                float v = fmaxf(acc[i][j][r] + bv, 0.f);
                ct[(size_t)(mb + r) * 256 + nn] = f2bf(v);
            }
        }
    }
    __syncthreads();
#pragma unroll
    for (int it = 0; it < 16; ++it) {
        const int row = it * 16 + (tid >> 5);
        const int colE = (tid & 31) * 8;
        *(int4*)(&C[(size_t)(m0 + row) * N + n0 + colE]) =
            *(const int4*)(ldsb + it * 8192 + (size_t)tid * 16);
    }
}

// ---------------- combine: out[b][t][o], 4 o's per thread ----------------
__global__ __launch_bounds__(256) void k_combine(const unsigned short* __restrict__ eo,
                                                 const float* __restrict__ g_all,
                                                 float* __restrict__ out) {
    int idx4 = blockIdx.x * 256 + threadIdx.x;    // over B*O/4
    int b = idx4 >> 7;                            // O/4 = 128
    int o4 = (idx4 & 127) * 4;
    const float* g = g_all + (size_t)b * 20;
    float v[E_SZ][4];
#pragma unroll
    for (int e = 0; e < E_SZ; ++e) {
        ushort4 u = *(const ushort4*)(eo + (size_t)e * B_SZ * O_SZ + (size_t)b * O_SZ + o4);
        v[e][0] = bf2f(u.x); v[e][1] = bf2f(u.y); v[e][2] = bf2f(u.z); v[e][3] = bf2f(u.w);
    }
    float4 r0, r1, r2;
    float* p0 = (float*)&r0; float* p1 = (float*)&r1; float* p2 = (float*)&r2;
#pragma unroll
    for (int c = 0; c < 4; ++c) {
        p0[c] = g[0] * v[0][c] + g[1] * v[1][c] + g[2] * v[4][c] + g[3] * v[5][c]
              + g[4] * v[6][c] + g[5] * v[7][c];
        p1[c] = g[6] * v[2][c] + g[7] * v[3][c] + g[8] * v[4][c] + g[9] * v[5][c]
              + g[10] * v[6][c] + g[11] * v[7][c];
        float s = 0.f;
#pragma unroll
        for (int e = 0; e < E_SZ; ++e) s += g[12 + e] * v[e][c];
        p2[c] = s;
    }
    size_t ob = (size_t)b * (3 * O_SZ) + o4;
    *(float4*)(out + ob) = r0;
    *(float4*)(out + ob + O_SZ) = r1;
    *(float4*)(out + ob + 2 * O_SZ) = r2;
}

extern "C" void kernel_launch(void* const* d_in, const int* in_sizes, int n_in,
                              void* d_out, int out_size, void* d_ws, size_t ws_size,
                              hipStream_t stream) {
    const float* x   = (const float*)d_in[0];
    const float* W1  = (const float*)d_in[1];
    const float* b1  = (const float*)d_in[2];
    const float* W2  = (const float*)d_in[3];
    const float* b2  = (const float*)d_in[4];
    const float* Wg  = (const float*)d_in[5];
    const float* Wgs = (const float*)d_in[6];
    float* out = (float*)d_out;

    char* ws = (char*)d_ws;
    const size_t SZ_XBF  = (size_t)B_SZ * D_SZ * 2;           // 16 MB
    const size_t SZ_W1T  = (size_t)E_SZ * H_SZ * D_SZ * 2;    // 16 MB
    const size_t SZ_W2T  = (size_t)E_SZ * O_SZ * H_SZ * 2;    // 8 MB
    const size_t SZ_EO   = (size_t)E_SZ * B_SZ * O_SZ * 2;    // 64 MB
    const size_t SZ_G    = (size_t)B_SZ * 20 * 4;             // 640 KB
    const size_t SZ_HBIG = (size_t)E_SZ * B_SZ * H_SZ * 2;    // 128 MB

    unsigned short* x_bf = (unsigned short*)ws;              ws += SZ_XBF;
    unsigned short* W1T  = (unsigned short*)ws;              ws += SZ_W1T;
    unsigned short* W2T  = (unsigned short*)ws;              ws += SZ_W2T;
    unsigned short* eo   = (unsigned short*)ws;              ws += SZ_EO;
    float* g_all         = (float*)ws;                       ws += SZ_G;
    unsigned short* h_buf = (unsigned short*)ws;

    const size_t fixed = SZ_XBF + SZ_W1T + SZ_W2T + SZ_EO + SZ_G;
    const bool big = ws_size >= fixed + SZ_HBIG;

    // 1) fused convert + gates; weight transposes
    k_convert_gates<<<B_SZ / 4, 256, 0, stream>>>(x, Wg, Wgs, x_bf, g_all);
    dim3 tb(64, 8);
    k_transpose_convert<<<dim3(H_SZ / 64, D_SZ / 64, E_SZ), tb, 0, stream>>>(W1, W1T, D_SZ, H_SZ);
    k_transpose_convert<<<dim3(O_SZ / 64, H_SZ / 64, E_SZ), tb, 0, stream>>>(W2, W2T, H_SZ, O_SZ);

    // 2) expert GEMMs (256x256 tiles; flat 1D grids, all % 8 == 0)
    if (big) {
        k_gemm_pipe<<<(H_SZ / 256) * (B_SZ / 256) * E_SZ, 512, 0, stream>>>(
            x_bf, W1T, b1, h_buf, B_SZ, H_SZ, D_SZ,
            0LL, (long long)H_SZ * D_SZ, (long long)H_SZ, (long long)B_SZ * H_SZ, 0);
        k_gemm_pipe<<<(O_SZ / 256) * (B_SZ / 256) * E_SZ, 512, 0, stream>>>(
            h_buf, W2T, b2, eo, B_SZ, O_SZ, H_SZ,
            (long long)B_SZ * H_SZ, (long long)O_SZ * H_SZ, (long long)O_SZ, (long long)B_SZ * O_SZ, 0);
    } else {
        for (int e = 0; e < E_SZ; ++e) {
            k_gemm_pipe<<<(H_SZ / 256) * (B_SZ / 256), 512, 0, stream>>>(
                x_bf, W1T, b1, h_buf, B_SZ, H_SZ, D_SZ,
                0LL, (long long)H_SZ * D_SZ, (long long)H_SZ, 0LL, e);
            k_gemm_pipe<<<(O_SZ / 256) * (B_SZ / 256), 512, 0, stream>>>(
                h_buf, W2T, b2, eo, B_SZ, O_SZ, H_SZ,
                0LL, (long long)O_SZ * H_SZ, (long long)O_SZ, (long long)B_SZ * O_SZ, e);
        }
    }

    // 3) combine
    k_combine<<<(B_SZ * O_SZ / 4) / 256, 256, 0, stream>>>(eo, g_all, out);
}